// Round 11
// baseline (53.137 us; speedup 1.0000x reference)
//
#include <hip/hip_runtime.h>

// LDDMM variational evolve: N-body Gaussian kernel sums, N=8192, D=3, fp32.
// dmom_i = (1/SIG2) * sum_j K_ij * <mom_i,mom_j> * (pos_i - pos_j)
// dpos_i = sum_j K_ij * mom_j
// K_ij = exp(-||xi-xj||^2/(2*SIG2)), SIG2=0.01 -> exp2(-72.1348*d2)
//
// Cell list: K < 4e-6 for d2 > 0.25; dropped-pair error ~1e-2 << thr 2.36.
// Ladder: R8 thread-serial 48us; R9 wave-per-point ~29us; R10 fused ~33us of
// kernel time -- irregular gather ran 10x above the ~4us arithmetic floor.
// R11: TILE-REGULARIZED. Tile=256 sorted points; union of neighbor boxes
// (superset of every member's 27-box) flattened to a virtual j-list (len U),
// split 64 ways (S=ceil(U/64)<=128 -> static LDS). Block = 1 wave, 4 i/lane
// (R3-R5: ILANES=4 balances VALU vs LDS pipe); dense broadcast eval loop ==
// brute-force loop shape at 13x fewer pairs. Partials[64] planes, no atomics.
// R7 NaN lesson: ci stays inside the exponent (arg <= 0 always).
// exp = __builtin_amdgcn_exp2f (plain exp2f -> OCML fixup; R2 measured).

#define NPTS  8192
#define NC    16
#define NCELL (NC * NC * NC)   // 4096
#define ORIGIN   (-4.0f)
#define INV_EDGE 2.0f          // edge 0.5
#define NTILE 32               // 8192 / 256
#define JSPLIT 64
#define SMAX  128              // ceil(NPTS/JSPLIT) upper bound on slice len

#define A_DOT 144.269504088896f     // 2*50*log2(e)
#define A_R   (-72.134752044448f)   // -50*log2(e)
#define INV_SIG2 100.0f

#define EXP2(x) __builtin_amdgcn_exp2f(x)

__device__ __forceinline__ int clampc(int c) { return min(max(c, 0), NC - 1); }

// ---------------- prep: hist (32 blocks) ----------------
__global__ __launch_bounds__(256)
void k_hist(const float* __restrict__ pos,
            int* __restrict__ cellid, int* __restrict__ rank,
            int* __restrict__ count)
{
    const int i = blockIdx.x * 256 + threadIdx.x;
    const float x = pos[3*i+0], y = pos[3*i+1], z = pos[3*i+2];
    const int cx = clampc((int)floorf((x - ORIGIN) * INV_EDGE));
    const int cy = clampc((int)floorf((y - ORIGIN) * INV_EDGE));
    const int cz = clampc((int)floorf((z - ORIGIN) * INV_EDGE));
    const int c = (cx * NC + cy) * NC + cz;
    cellid[i] = c;
    rank[i] = atomicAdd(&count[c], 1);
}

// ---------------- prep: scan 4096 bins, 1 block 1024 threads, 3 barriers ----
__global__ __launch_bounds__(1024)
void k_scan(const int* __restrict__ count, int* __restrict__ start)
{
    __shared__ int wtot[16];
    __shared__ int wexcl[16];
    const int t = threadIdx.x;
    const int lane = t & 63;
    const int wid = t >> 6;

    int b0 = count[4*t+0], b1 = count[4*t+1], b2 = count[4*t+2], b3 = count[4*t+3];
    const int s = b0 + b1 + b2 + b3;

    // wave inclusive scan of s
    int p = s;
    #pragma unroll
    for (int off = 1; off < 64; off <<= 1) {
        const int v = __shfl_up(p, off);
        if (lane >= off) p += v;
    }
    if (lane == 63) wtot[wid] = p;
    __syncthreads();
    if (t < 16) {
        int w = wtot[t];
        int q = w;
        #pragma unroll
        for (int off = 1; off < 16; off <<= 1) {
            const int v = __shfl_up(q, off);
            if (t >= off) q += v;
        }
        wexcl[t] = q - w;
    }
    __syncthreads();
    const int base = wexcl[wid] + (p - s);   // exclusive prefix for thread t
    start[4*t+0] = base;
    start[4*t+1] = base + b0;
    start[4*t+2] = base + b0 + b1;
    start[4*t+3] = base + b0 + b1 + b2;
    if (t == 0) start[NCELL] = NPTS;
}

// ---------------- prep: scatter (32 blocks) ----------------
__global__ __launch_bounds__(256)
void k_scatter(const float* __restrict__ mom, const float* __restrict__ pos,
               const int* __restrict__ cellid, const int* __restrict__ rank,
               const int* __restrict__ start,
               float* __restrict__ pmP, float* __restrict__ pmM,
               float* __restrict__ pmR, int* __restrict__ inv)
{
    const int i = blockIdx.x * 256 + threadIdx.x;
    const int cid = cellid[i];
    const int dst = start[cid] + rank[i];
    const float x = pos[3*i+0], y = pos[3*i+1], z = pos[3*i+2];
    const float r2 = x*x + y*y + z*z;
    reinterpret_cast<float4*>(pmP)[dst] = make_float4(A_DOT*x, A_DOT*y, A_DOT*z, A_R*r2);
    reinterpret_cast<float4*>(pmM)[dst] = make_float4(mom[3*i+0], mom[3*i+1], mom[3*i+2], 0.0f);
    reinterpret_cast<float4*>(pmR)[dst] = make_float4(x, y, z, __int_as_float(cid));
    inv[dst] = i;
}

// ---------------- main: block = (tile, slice c), 1 wave, 4 i-points/lane ----
__device__ __forceinline__ void eval_one(
    const float4 P, const float4 M,
    const float xi, const float yi, const float zi, const float ci,
    const float pxi, const float pyi, const float pzi,
    float& Sa, float& SPx, float& SPy, float& SPz,
    float& apx, float& apy, float& apz)
{
    // arg = ci + A_DOT*<xi,xj> + A_R*rj2 = -72.13*d2 <= 0 (no overflow)
    float arg = __builtin_fmaf(zi, P.z, ci + P.w);
    arg = __builtin_fmaf(yi, P.y, arg);
    arg = __builtin_fmaf(xi, P.x, arg);
    const float K = EXP2(arg);
    const float C = __builtin_fmaf(pzi, M.z, __builtin_fmaf(pyi, M.y, pxi * M.x));
    const float s = K * C;
    Sa += s;
    SPx = __builtin_fmaf(s, P.x, SPx);
    SPy = __builtin_fmaf(s, P.y, SPy);
    SPz = __builtin_fmaf(s, P.z, SPz);
    apx = __builtin_fmaf(K, M.x, apx);
    apy = __builtin_fmaf(K, M.y, apy);
    apz = __builtin_fmaf(K, M.z, apz);
}

__global__ __launch_bounds__(64)
void k_main(const float* __restrict__ pmP, const float* __restrict__ pmM,
            const float* __restrict__ pmR, const int* __restrict__ start,
            float* __restrict__ partial)
{
    __shared__ float4 ldsP[SMAX];
    __shared__ float4 ldsM[SMAX];

    const int tile = blockIdx.x >> 6;        // 0..31
    const int c    = blockIdx.x & 63;        // slice 0..63
    const int lane = threadIdx.x;            // 0..63

    // ---- load my 4 i-points (coalesced) ----
    float xi[4], yi[4], zi[4], pxi[4], pyi[4], pzi[4], ci[4];
    int mincx = NC, maxcx = -1, mincy = NC, maxcy = -1, mincz = NC, maxcz = -1;
    #pragma unroll
    for (int k = 0; k < 4; ++k) {
        const int si = tile * 256 + k * 64 + lane;
        const float4 R = reinterpret_cast<const float4*>(pmR)[si];
        const float4 M = reinterpret_cast<const float4*>(pmM)[si];
        xi[k] = R.x; yi[k] = R.y; zi[k] = R.z;
        pxi[k] = M.x; pyi[k] = M.y; pzi[k] = M.z;
        ci[k] = A_R * (R.x*R.x + R.y*R.y + R.z*R.z);
        const int cid = __float_as_int(R.w);
        const int cx = cid >> 8, cy = (cid >> 4) & 15, cz = cid & 15;
        mincx = min(mincx, cx); maxcx = max(maxcx, cx);
        mincy = min(mincy, cy); maxcy = max(maxcy, cy);
        mincz = min(mincz, cz); maxcz = max(maxcz, cz);
    }
    // wave-reduce bbox
    #pragma unroll
    for (int off = 1; off < 64; off <<= 1) {
        mincx = min(mincx, __shfl_xor(mincx, off));
        maxcx = max(maxcx, __shfl_xor(maxcx, off));
        mincy = min(mincy, __shfl_xor(mincy, off));
        maxcy = max(maxcy, __shfl_xor(maxcy, off));
        mincz = min(mincz, __shfl_xor(mincz, off));
        maxcz = max(maxcz, __shfl_xor(maxcz, off));
    }
    const int lox = clampc(mincx - 1), hix = clampc(maxcx + 1);
    const int loy = clampc(mincy - 1), hiy = clampc(maxcy + 1);
    const int loz = clampc(mincz - 1), hiz = clampc(maxcz + 1);
    const int CY = hiy - loy + 1;
    const int ncols = (hix - lox + 1) * CY;

    // ---- pass 1: total union length U ----
    int U = 0;
    for (int cb = 0; cb < ncols; cb += 64) {
        const int l = cb + lane;
        int len = 0;
        if (l < ncols) {
            const int nx = lox + l / CY, ny = loy + l % CY;
            const int base = (nx * NC + ny) * NC;
            len = start[base + hiz + 1] - start[base + loz];
        }
        #pragma unroll
        for (int off = 1; off < 64; off <<= 1) len += __shfl_xor(len, off);
        U += len;
    }
    const int Ssl = (U + 63) >> 6;           // slice size, <= SMAX
    const int slo = c * Ssl;
    const int shi = min(U, slo + Ssl);
    const int n = max(0, shi - slo);

    // ---- pass 2: stage my slice (coalesced per column intersection) ----
    if (n > 0) {
        const float4* pmPv = reinterpret_cast<const float4*>(pmP);
        const float4* pmMv = reinterpret_cast<const float4*>(pmM);
        int vbase = 0;
        for (int cb = 0; cb < ncols && vbase < shi; cb += 64) {
            const int l = cb + lane;
            int st = 0, len = 0;
            if (l < ncols) {
                const int nx = lox + l / CY, ny = loy + l % CY;
                const int base = (nx * NC + ny) * NC;
                st = start[base + loz];
                len = start[base + hiz + 1] - st;
            }
            int p = len;
            #pragma unroll
            for (int off = 1; off < 64; off <<= 1) {
                const int v = __shfl_up(p, off);
                if (lane >= off) p += v;
            }
            const int chunk_total = __shfl(p, 63);
            const int nc_ch = min(64, ncols - cb);
            for (int q = 0; q < nc_ch; ++q) {
                const int lenq = __shfl(len, q);
                const int vst  = vbase + __shfl(p, q) - lenq;
                if (vst >= shi) break;
                if (vst + lenq <= slo) continue;
                const int stq = __shfl(st, q);
                const int lo = max(slo - vst, 0);
                const int hi = min(lenq, shi - vst);
                for (int r = lo + lane; r < hi; r += 64) {
                    const int d = vst + r - slo;
                    ldsP[d] = pmPv[stq + r];
                    ldsM[d] = pmMv[stq + r];
                }
            }
            vbase += chunk_total;
        }
    }
    __syncthreads();   // single wave: compiles to waitcnt

    // ---- dense eval loop (brute-force shape) ----
    float Sa[4], SPx[4], SPy[4], SPz[4], apx[4], apy[4], apz[4];
    #pragma unroll
    for (int k = 0; k < 4; ++k) {
        Sa[k]=0.f; SPx[k]=0.f; SPy[k]=0.f; SPz[k]=0.f;
        apx[k]=0.f; apy[k]=0.f; apz[k]=0.f;
    }
    #pragma unroll 2
    for (int jj = 0; jj < n; ++jj) {
        const float4 P = ldsP[jj];   // broadcast ds_read_b128
        const float4 M = ldsM[jj];
        #pragma unroll
        for (int k = 0; k < 4; ++k)
            eval_one(P, M, xi[k], yi[k], zi[k], ci[k], pxi[k], pyi[k], pzi[k],
                     Sa[k], SPx[k], SPy[k], SPz[k], apx[k], apy[k], apz[k]);
    }

    // ---- write my plane of partials (fully covered, zeros included) ----
    const float us = INV_SIG2 / A_DOT;
    float* base = partial + (size_t)c * 6 * NPTS;
    #pragma unroll
    for (int k = 0; k < 4; ++k) {
        const int si = tile * 256 + k * 64 + lane;
        base[0*NPTS + si] = INV_SIG2 * xi[k] * Sa[k] - us * SPx[k];
        base[1*NPTS + si] = INV_SIG2 * yi[k] * Sa[k] - us * SPy[k];
        base[2*NPTS + si] = INV_SIG2 * zi[k] * Sa[k] - us * SPz[k];
        base[3*NPTS + si] = apx[k];
        base[4*NPTS + si] = apy[k];
        base[5*NPTS + si] = apz[k];
    }
}

// ---------------- reduce 64 planes, map sorted -> original ----------------
__global__ __launch_bounds__(256)
void k_reduce(const float* __restrict__ partial, const int* __restrict__ inv,
              float* __restrict__ out)
{
    const int idx = blockIdx.x * 256 + threadIdx.x;   // 0 .. 6*NPTS-1
    const int comp = idx >> 13;
    const int si   = idx & (NPTS - 1);
    float s = 0.0f;
    #pragma unroll 8
    for (int c = 0; c < JSPLIT; ++c)
        s += partial[(size_t)c * 6 * NPTS + (size_t)comp * NPTS + si];
    const int oi = inv[si];
    if (comp < 3) out[3*oi + comp] = s;
    else          out[3*NPTS + 3*oi + (comp - 3)] = s;
}

extern "C" void kernel_launch(void* const* d_in, const int* in_sizes, int n_in,
                              void* d_out, int out_size, void* d_ws, size_t ws_size,
                              hipStream_t stream)
{
    const float* mom = (const float*)d_in[0];
    const float* pos = (const float*)d_in[1];
    float* out = (float*)d_out;

    // ws layout
    float* pmP  = (float*)d_ws;                         // 128 KB
    float* pmM  = pmP + (size_t)4 * NPTS;               // 128 KB
    float* pmR  = pmM + (size_t)4 * NPTS;               // 128 KB
    float* partial = pmR + (size_t)4 * NPTS;            // 64*6*NPTS*4 = 12.6 MB
    int* inv    = (int*)(partial + (size_t)JSPLIT * 6 * NPTS);
    int* cellid = inv + NPTS;
    int* rank   = cellid + NPTS;
    int* count  = rank + NPTS;
    int* start  = count + NCELL;

    hipMemsetAsync(count, 0, NCELL * sizeof(int), stream);
    k_hist<<<NPTS / 256, 256, 0, stream>>>(pos, cellid, rank, count);
    k_scan<<<1, 1024, 0, stream>>>(count, start);
    k_scatter<<<NPTS / 256, 256, 0, stream>>>(mom, pos, cellid, rank, start,
                                              pmP, pmM, pmR, inv);
    k_main<<<NTILE * JSPLIT, 64, 0, stream>>>(pmP, pmM, pmR, start, partial);
    k_reduce<<<(6 * NPTS) / 256, 256, 0, stream>>>(partial, inv, out);
}

// Round 12
// 29.894 us; speedup vs baseline: 1.7775x; 1.7775x over previous
//
#include <hip/hip_runtime.h>

// LDDMM variational evolve: N-body Gaussian kernel sums, N=8192, D=3, fp32.
// dmom_i = (1/SIG2) * sum_j K_ij * <mom_i,mom_j> * (pos_i - pos_j)
// dpos_i = sum_j K_ij * mom_j
// K_ij = exp(-||xi-xj||^2/(2*SIG2)), SIG2=0.01 -> exp2(-72.1348*d2)
//
// Cell list: K < 4e-6 for d2 > 0.25; dropped-pair error ~1e-2 << thr 2.36.
// Ladder: R8 thread-serial 48us (imbalance); R9 wave-per-point 27-cell loop
// ~20us (13% lane fill); R10 fused-prep 35us total; R11 tile-bbox union
// REGRESSED 53us (lexicographic tiles have huge bboxes). R12: wave-per-point
// with Z-MERGED COLUMN RANGES -- the 9 (x,y)-neighbor columns are contiguous
// in the sorted array over z in [cz-1,cz+1]: <=9 ranges x ~60 pts = ~95%
// lane fill; 8192 waves = 8/SIMD. Prep fully parallel, 4 dispatches, no
// memset (countscan zeroes LDS bins itself; scatter ranks via atomic cursor).
// R7 NaN lesson: ci stays inside the exponent (arg <= 0 always).
// exp = __builtin_amdgcn_exp2f (plain exp2f -> OCML fixup; R2 measured).

#define NPTS  8192
#define NC    16
#define NCELL (NC * NC * NC)   // 4096
#define ORIGIN   (-4.0f)
#define INV_EDGE 2.0f          // edge 0.5

#define A_DOT 144.269504088896f     // 2*50*log2(e)
#define A_R   (-72.134752044448f)   // -50*log2(e)
#define INV_SIG2 100.0f

#define EXP2(x) __builtin_amdgcn_exp2f(x)

__device__ __forceinline__ int clampc(int c) { return min(max(c, 0), NC - 1); }

// ---------------- prep 1: cell ids (no atomics, no zeroed state) ----------------
__global__ __launch_bounds__(256)
void k_cellid(const float* __restrict__ pos, int* __restrict__ cellid)
{
    const int i = blockIdx.x * 256 + threadIdx.x;
    const float x = pos[3*i+0], y = pos[3*i+1], z = pos[3*i+2];
    const int cx = clampc((int)floorf((x - ORIGIN) * INV_EDGE));
    const int cy = clampc((int)floorf((y - ORIGIN) * INV_EDGE));
    const int cz = clampc((int)floorf((z - ORIGIN) * INV_EDGE));
    cellid[i] = (cx * NC + cy) * NC + cz;
}

// ---------------- prep 2: count (LDS) + scan, one block ----------------
__global__ __launch_bounds__(1024)
void k_countscan(const int* __restrict__ cellid,
                 int* __restrict__ start, int* __restrict__ cur)
{
    __shared__ int cnt[NCELL];
    __shared__ int wtot[16];
    __shared__ int wexcl[16];
    const int t = threadIdx.x;
    const int lane = t & 63;
    const int wid = t >> 6;

    #pragma unroll
    for (int k = 0; k < NCELL / 1024; ++k) cnt[t + k * 1024] = 0;
    __syncthreads();

    #pragma unroll
    for (int k = 0; k < NPTS / 1024; ++k)
        atomicAdd(&cnt[cellid[t + k * 1024]], 1);
    __syncthreads();

    // scan 4096 bins: thread t owns cells 4t..4t+3
    const int b0 = cnt[4*t+0], b1 = cnt[4*t+1], b2 = cnt[4*t+2], b3 = cnt[4*t+3];
    const int s = b0 + b1 + b2 + b3;
    int p = s;
    #pragma unroll
    for (int off = 1; off < 64; off <<= 1) {
        const int v = __shfl_up(p, off);
        if (lane >= off) p += v;
    }
    if (lane == 63) wtot[wid] = p;
    __syncthreads();
    if (t < 16) {
        const int w = wtot[t];
        int q = w;
        #pragma unroll
        for (int off = 1; off < 16; off <<= 1) {
            const int v = __shfl_up(q, off);
            if (t >= off) q += v;
        }
        wexcl[t] = q - w;
    }
    __syncthreads();
    const int base = wexcl[wid] + (p - s);
    start[4*t+0] = base;
    start[4*t+1] = base + b0;
    start[4*t+2] = base + b0 + b1;
    start[4*t+3] = base + b0 + b1 + b2;
    cur[4*t+0] = base;
    cur[4*t+1] = base + b0;
    cur[4*t+2] = base + b0 + b1;
    cur[4*t+3] = base + b0 + b1 + b2;
    if (t == 0) start[NCELL] = NPTS;
}

// ---------------- prep 3: scatter (parallel, atomic cursor ranks) ----------------
__global__ __launch_bounds__(256)
void k_scatter(const float* __restrict__ mom, const float* __restrict__ pos,
               const int* __restrict__ cellid, int* __restrict__ cur,
               float* __restrict__ pmP, float* __restrict__ pmM,
               int* __restrict__ inv)
{
    const int i = blockIdx.x * 256 + threadIdx.x;
    const int dst = atomicAdd(&cur[cellid[i]], 1);
    const float x = pos[3*i+0], y = pos[3*i+1], z = pos[3*i+2];
    const float r2 = x*x + y*y + z*z;
    reinterpret_cast<float4*>(pmP)[dst] = make_float4(A_DOT*x, A_DOT*y, A_DOT*z, A_R*r2);
    reinterpret_cast<float4*>(pmM)[dst] = make_float4(mom[3*i+0], mom[3*i+1], mom[3*i+2], 0.0f);
    inv[dst] = i;
}

// ---------------- main: one wave per point, <=9 z-merged column ranges ----------------
__global__ __launch_bounds__(256)
void k_main(const float* __restrict__ mom, const float* __restrict__ pos,
            const float* __restrict__ pmP, const float* __restrict__ pmM,
            const int* __restrict__ inv, const int* __restrict__ start,
            float* __restrict__ out)
{
    const int wid  = (blockIdx.x * 256 + threadIdx.x) >> 6;   // 0..8191
    const int lane = threadIdx.x & 63;

    const int oi = inv[wid];                                  // wave-uniform
    const float xi = pos[3*oi+0], yi = pos[3*oi+1], zi = pos[3*oi+2];
    const float pxi = mom[3*oi+0], pyi = mom[3*oi+1], pzi = mom[3*oi+2];
    const float ci  = A_R * (xi*xi + yi*yi + zi*zi);

    const int cx = clampc((int)floorf((xi - ORIGIN) * INV_EDGE));
    const int cy = clampc((int)floorf((yi - ORIGIN) * INV_EDGE));
    const int cz = clampc((int)floorf((zi - ORIGIN) * INV_EDGE));
    const int x0 = max(cx - 1, 0), x1 = min(cx + 1, NC - 1);
    const int y0 = max(cy - 1, 0), y1 = min(cy + 1, NC - 1);
    const int z0 = max(cz - 1, 0), z1 = min(cz + 1, NC - 1);
    const int wy = y1 - y0 + 1;
    const int ncol = (x1 - x0 + 1) * wy;                      // 4..9

    // Lanes 0..ncol-1: (st,en) of this column's z-merged contiguous range.
    int st_l = 0, en_l = 0;
    if (lane < ncol) {
        const int nx = x0 + lane / wy;
        const int ny = y0 + lane % wy;
        const int base = (nx * NC + ny) * NC;
        st_l = start[base + z0];
        en_l = start[base + z1 + 1];
    }

    float S = 0.f, SPx = 0.f, SPy = 0.f, SPz = 0.f;
    float apx = 0.f, apy = 0.f, apz = 0.f;

    const float4* __restrict__ pmPv = reinterpret_cast<const float4*>(pmP);
    const float4* __restrict__ pmMv = reinterpret_cast<const float4*>(pmM);

    for (int p = 0; p < ncol; ++p) {
        const int st = __shfl(st_l, p);
        const int en = __shfl(en_l, p);
        for (int j = st + lane; j < en; j += 64) {
            const float4 P = pmPv[j];                         // coalesced
            const float4 M = pmMv[j];
            // arg = ci + A_DOT*<xi,xj> + A_R*rj2 = -72.13*d2 <= 0 (no overflow)
            float arg = __builtin_fmaf(zi, P.z, ci + P.w);
            arg = __builtin_fmaf(yi, P.y, arg);
            arg = __builtin_fmaf(xi, P.x, arg);
            const float K = EXP2(arg);
            const float C = __builtin_fmaf(pzi, M.z,
                              __builtin_fmaf(pyi, M.y, pxi * M.x));
            const float s = K * C;
            S += s;
            SPx = __builtin_fmaf(s, P.x, SPx);
            SPy = __builtin_fmaf(s, P.y, SPy);
            SPz = __builtin_fmaf(s, P.z, SPz);
            apx = __builtin_fmaf(K, M.x, apx);
            apy = __builtin_fmaf(K, M.y, apy);
            apz = __builtin_fmaf(K, M.z, apz);
        }
    }

    // 64-lane butterfly reduce of the 7 accumulators.
    #pragma unroll
    for (int off = 1; off < 64; off <<= 1) {
        S   += __shfl_xor(S,   off);
        SPx += __shfl_xor(SPx, off);
        SPy += __shfl_xor(SPy, off);
        SPz += __shfl_xor(SPz, off);
        apx += __shfl_xor(apx, off);
        apy += __shfl_xor(apy, off);
        apz += __shfl_xor(apz, off);
    }

    if (lane == 0) {
        const float us = INV_SIG2 / A_DOT;
        out[3*oi+0] = INV_SIG2 * xi * S - us * SPx;
        out[3*oi+1] = INV_SIG2 * yi * S - us * SPy;
        out[3*oi+2] = INV_SIG2 * zi * S - us * SPz;
        out[3*NPTS + 3*oi+0] = apx;
        out[3*NPTS + 3*oi+1] = apy;
        out[3*NPTS + 3*oi+2] = apz;
    }
}

extern "C" void kernel_launch(void* const* d_in, const int* in_sizes, int n_in,
                              void* d_out, int out_size, void* d_ws, size_t ws_size,
                              hipStream_t stream)
{
    const float* mom = (const float*)d_in[0];
    const float* pos = (const float*)d_in[1];
    float* out = (float*)d_out;

    // ws layout: pmP (4*NPTS f), pmM (4*NPTS f), inv, cellid (NPTS i),
    //            start (NCELL+1 i), cur (NCELL i)  -> ~330 KB
    float* pmP  = (float*)d_ws;
    float* pmM  = pmP + (size_t)4 * NPTS;
    int* inv    = (int*)(pmM + (size_t)4 * NPTS);
    int* cellid = inv + NPTS;
    int* start  = cellid + NPTS;
    int* cur    = start + NCELL + 1;

    k_cellid<<<NPTS / 256, 256, 0, stream>>>(pos, cellid);
    k_countscan<<<1, 1024, 0, stream>>>(cellid, start, cur);
    k_scatter<<<NPTS / 256, 256, 0, stream>>>(mom, pos, cellid, cur, pmP, pmM, inv);
    k_main<<<(NPTS * 64) / 256, 256, 0, stream>>>(mom, pos, pmP, pmM, inv, start, out);
}

// Round 13
// 24.861 us; speedup vs baseline: 2.1374x; 1.2025x over previous
//
#include <hip/hip_runtime.h>

// LDDMM variational evolve: N-body Gaussian kernel sums, N=8192, D=3, fp32.
// dmom_i = (1/SIG2) * sum_j K_ij * <mom_i,mom_j> * (pos_i - pos_j)
// dpos_i = sum_j K_ij * mom_j
// K_ij = exp(-||xi-xj||^2/(2*SIG2)), SIG2=0.01 -> exp2(-72.1348*d2)
//
// Cell list: K < 4e-6 for d2 > 0.25; dropped-pair error ~1e-2 << thr 2.36.
// Ladder: R9 wave-per-point 27-cell ~36.5; R12 z-merged columns + parallel
// prep 29.9. R13: (1) fold cellid kernel into countscan+scatter (recompute
// beats kernel+array roundtrip; 4->3 dispatches); (2) Z-REFINED slabs
// (0.25, NCZ=32): clip each of the 9 columns to the EXACT z-window
// [zi-0.5, zi+0.5] -> ~25% fewer pair evals, same 9-column wave shape.
// All dropped pairs have d2 > 0.25 (in budget).
// R7 NaN lesson: ci stays inside the exponent (arg <= 0 always).
// exp = __builtin_amdgcn_exp2f (plain exp2f -> OCML fixup; R2 measured).

#define NPTS  8192
#define NCXY  16
#define NCZ   32
#define NCELL (NCXY * NCXY * NCZ)   // 8192
#define ORIGIN    (-4.0f)
#define INV_EDGE  2.0f              // xy edge 0.5
#define INV_EDGEZ 4.0f              // z slab 0.25
#define RCUT      0.5f

#define A_DOT 144.269504088896f     // 2*50*log2(e)
#define A_R   (-72.134752044448f)   // -50*log2(e)
#define INV_SIG2 100.0f

#define EXP2(x) __builtin_amdgcn_exp2f(x)

__device__ __forceinline__ int clampi(int c, int hi) { return min(max(c, 0), hi); }

__device__ __forceinline__ int cell_of(float x, float y, float z) {
    const int cx = clampi((int)floorf((x - ORIGIN) * INV_EDGE),  NCXY - 1);
    const int cy = clampi((int)floorf((y - ORIGIN) * INV_EDGE),  NCXY - 1);
    const int cz = clampi((int)floorf((z - ORIGIN) * INV_EDGEZ), NCZ  - 1);
    return (cx * NCXY + cy) * NCZ + cz;
}

// ---------------- prep 1: count (LDS hist) + scan, one block ----------------
__global__ __launch_bounds__(1024)
void k_countscan(const float* __restrict__ pos,
                 int* __restrict__ start, int* __restrict__ cur)
{
    __shared__ int cnt[NCELL];      // 32 KB
    __shared__ int wtot[16];
    __shared__ int wexcl[16];
    const int t = threadIdx.x;
    const int lane = t & 63;
    const int wid = t >> 6;

    #pragma unroll
    for (int k = 0; k < NCELL / 1024; ++k) cnt[t + k * 1024] = 0;
    __syncthreads();

    #pragma unroll
    for (int k = 0; k < NPTS / 1024; ++k) {
        const int i = t + k * 1024;
        atomicAdd(&cnt[cell_of(pos[3*i+0], pos[3*i+1], pos[3*i+2])], 1);
    }
    __syncthreads();

    // scan 8192 bins: thread t owns cells 8t..8t+7
    int pre[8];
    int s = 0;
    #pragma unroll
    for (int k = 0; k < 8; ++k) { pre[k] = s; s += cnt[8*t + k]; }
    int p = s;
    #pragma unroll
    for (int off = 1; off < 64; off <<= 1) {
        const int v = __shfl_up(p, off);
        if (lane >= off) p += v;
    }
    if (lane == 63) wtot[wid] = p;
    __syncthreads();
    if (t < 16) {
        const int w = wtot[t];
        int q = w;
        #pragma unroll
        for (int off = 1; off < 16; off <<= 1) {
            const int v = __shfl_up(q, off);
            if (t >= off) q += v;
        }
        wexcl[t] = q - w;
    }
    __syncthreads();
    const int base = wexcl[wid] + (p - s);
    #pragma unroll
    for (int k = 0; k < 8; ++k) {
        const int v = base + pre[k];
        start[8*t + k] = v;
        cur[8*t + k] = v;
    }
    if (t == 0) start[NCELL] = NPTS;
}

// ---------------- prep 2: scatter (parallel, atomic cursor ranks) ----------------
__global__ __launch_bounds__(256)
void k_scatter(const float* __restrict__ mom, const float* __restrict__ pos,
               int* __restrict__ cur,
               float* __restrict__ pmP, float* __restrict__ pmM,
               int* __restrict__ inv)
{
    const int i = blockIdx.x * 256 + threadIdx.x;
    const float x = pos[3*i+0], y = pos[3*i+1], z = pos[3*i+2];
    const int dst = atomicAdd(&cur[cell_of(x, y, z)], 1);
    const float r2 = x*x + y*y + z*z;
    reinterpret_cast<float4*>(pmP)[dst] = make_float4(A_DOT*x, A_DOT*y, A_DOT*z, A_R*r2);
    reinterpret_cast<float4*>(pmM)[dst] = make_float4(mom[3*i+0], mom[3*i+1], mom[3*i+2], 0.0f);
    inv[dst] = i;
}

// ---------------- main: one wave per point, 9 columns x exact z-window ----------------
__global__ __launch_bounds__(256)
void k_main(const float* __restrict__ mom, const float* __restrict__ pos,
            const float* __restrict__ pmP, const float* __restrict__ pmM,
            const int* __restrict__ inv, const int* __restrict__ start,
            float* __restrict__ out)
{
    const int wid  = (blockIdx.x * 256 + threadIdx.x) >> 6;   // 0..8191
    const int lane = threadIdx.x & 63;

    const int oi = inv[wid];                                  // wave-uniform
    const float xi = pos[3*oi+0], yi = pos[3*oi+1], zi = pos[3*oi+2];
    const float pxi = mom[3*oi+0], pyi = mom[3*oi+1], pzi = mom[3*oi+2];
    const float ci  = A_R * (xi*xi + yi*yi + zi*zi);

    const int cx = clampi((int)floorf((xi - ORIGIN) * INV_EDGE), NCXY - 1);
    const int cy = clampi((int)floorf((yi - ORIGIN) * INV_EDGE), NCXY - 1);
    const int x0 = max(cx - 1, 0), x1 = min(cx + 1, NCXY - 1);
    const int y0 = max(cy - 1, 0), y1 = min(cy + 1, NCXY - 1);
    // exact z-window, slab-granular (every |dz|<=RCUT pair retained)
    const int z0 = clampi((int)floorf((zi - RCUT - ORIGIN) * INV_EDGEZ), NCZ - 1);
    const int z1 = clampi((int)floorf((zi + RCUT - ORIGIN) * INV_EDGEZ), NCZ - 1);
    const int wy = y1 - y0 + 1;
    const int ncol = (x1 - x0 + 1) * wy;                      // 4..9

    // Lanes 0..ncol-1: (st,en) of this column's z-clipped contiguous range.
    int st_l = 0, en_l = 0;
    if (lane < ncol) {
        const int nx = x0 + lane / wy;
        const int ny = y0 + lane % wy;
        const int base = (nx * NCXY + ny) * NCZ;
        st_l = start[base + z0];
        en_l = start[base + z1 + 1];
    }

    float S = 0.f, SPx = 0.f, SPy = 0.f, SPz = 0.f;
    float apx = 0.f, apy = 0.f, apz = 0.f;

    const float4* __restrict__ pmPv = reinterpret_cast<const float4*>(pmP);
    const float4* __restrict__ pmMv = reinterpret_cast<const float4*>(pmM);

    for (int p = 0; p < ncol; ++p) {
        const int st = __shfl(st_l, p);
        const int en = __shfl(en_l, p);
        for (int j = st + lane; j < en; j += 64) {
            const float4 P = pmPv[j];                         // coalesced
            const float4 M = pmMv[j];
            // arg = ci + A_DOT*<xi,xj> + A_R*rj2 = -72.13*d2 <= 0 (no overflow)
            float arg = __builtin_fmaf(zi, P.z, ci + P.w);
            arg = __builtin_fmaf(yi, P.y, arg);
            arg = __builtin_fmaf(xi, P.x, arg);
            const float K = EXP2(arg);
            const float C = __builtin_fmaf(pzi, M.z,
                              __builtin_fmaf(pyi, M.y, pxi * M.x));
            const float s = K * C;
            S += s;
            SPx = __builtin_fmaf(s, P.x, SPx);
            SPy = __builtin_fmaf(s, P.y, SPy);
            SPz = __builtin_fmaf(s, P.z, SPz);
            apx = __builtin_fmaf(K, M.x, apx);
            apy = __builtin_fmaf(K, M.y, apy);
            apz = __builtin_fmaf(K, M.z, apz);
        }
    }

    // 64-lane butterfly reduce of the 7 accumulators.
    #pragma unroll
    for (int off = 1; off < 64; off <<= 1) {
        S   += __shfl_xor(S,   off);
        SPx += __shfl_xor(SPx, off);
        SPy += __shfl_xor(SPy, off);
        SPz += __shfl_xor(SPz, off);
        apx += __shfl_xor(apx, off);
        apy += __shfl_xor(apy, off);
        apz += __shfl_xor(apz, off);
    }

    if (lane == 0) {
        const float us = INV_SIG2 / A_DOT;
        out[3*oi+0] = INV_SIG2 * xi * S - us * SPx;
        out[3*oi+1] = INV_SIG2 * yi * S - us * SPy;
        out[3*oi+2] = INV_SIG2 * zi * S - us * SPz;
        out[3*NPTS + 3*oi+0] = apx;
        out[3*NPTS + 3*oi+1] = apy;
        out[3*NPTS + 3*oi+2] = apz;
    }
}

extern "C" void kernel_launch(void* const* d_in, const int* in_sizes, int n_in,
                              void* d_out, int out_size, void* d_ws, size_t ws_size,
                              hipStream_t stream)
{
    const float* mom = (const float*)d_in[0];
    const float* pos = (const float*)d_in[1];
    float* out = (float*)d_out;

    // ws layout: pmP (4*NPTS f), pmM (4*NPTS f), inv (NPTS i),
    //            start (NCELL+1 i), cur (NCELL i)  -> ~355 KB
    float* pmP  = (float*)d_ws;
    float* pmM  = pmP + (size_t)4 * NPTS;
    int* inv    = (int*)(pmM + (size_t)4 * NPTS);
    int* start  = inv + NPTS;
    int* cur    = start + NCELL + 1;

    k_countscan<<<1, 1024, 0, stream>>>(pos, start, cur);
    k_scatter<<<NPTS / 256, 256, 0, stream>>>(mom, pos, cur, pmP, pmM, inv);
    k_main<<<(NPTS * 64) / 256, 256, 0, stream>>>(mom, pos, pmP, pmM, inv, start, out);
}